// Round 1
// baseline (232.661 us; speedup 1.0000x reference)
//
#include <hip/hip_runtime.h>

// Gaussian RBF weighted sum:
//   out[b] = sum_g exp(-(||x_b||^2 + ||c_g||^2 - 2 x_b.c_g)/2) * w[g]
// B=16384, G=8192, D=64, fp32. Compute-bound: 17.18 GFLOP of dots.
// v1: fp32 VALU register-tiled (no fp32 MFMA on CDNA4). 128x128 tile,
// 8x8 per thread, K=64 staged transposed in LDS. GSPLIT=4 -> 512 blocks
// (2 blocks/CU at 77.3KB LDS), partials via atomicAdd on zeroed out.

#define TILE_D 64
#define BM 128
#define BN 128
#define GSPLIT 4
#define PADM (BM + 4)   // row stride 132 floats: keeps float4 alignment (132%4==0)

__global__ __launch_bounds__(256, 2)
void gauss_rbf_kernel(const float* __restrict__ X,
                      const float* __restrict__ C,
                      const float* __restrict__ W,
                      float* __restrict__ out,
                      int B, int G) {
    __shared__ float xs[TILE_D][PADM];   // xs[d][m] = X[bm0+m][d]
    __shared__ float cs[TILE_D][PADM];   // cs[d][n] = C[g0+n][d]
    __shared__ float red[BM][17];
    __shared__ float xnorm[BM];          // -0.5*log2e*||x||^2
    __shared__ float cnorm[BN];          // -0.5*log2e*||c||^2

    const int tid = threadIdx.x;
    const int tx  = tid & 15;
    const int ty  = tid >> 4;
    const int bm0 = blockIdx.x * BM;
    const int gchunk = G / GSPLIT;
    const int g0base = blockIdx.y * gchunk;

    const int d     = tid & 63;
    const int rbase = (tid >> 6) * 4;

    // ---- stage X tile (BM x 64) transposed into xs[d][m] ----
    {
        const float* Xs = X + (size_t)bm0 * TILE_D;
        #pragma unroll
        for (int p = 0; p < BM; p += 16) {
            int r = p + rbase;
            float4 v;
            v.x = Xs[(size_t)(r + 0) * TILE_D + d];
            v.y = Xs[(size_t)(r + 1) * TILE_D + d];
            v.z = Xs[(size_t)(r + 2) * TILE_D + d];
            v.w = Xs[(size_t)(r + 3) * TILE_D + d];
            *(float4*)&xs[d][r] = v;
        }
    }
    __syncthreads();
    if (tid < BM) {
        float s = 0.f;
        #pragma unroll
        for (int k = 0; k < TILE_D; ++k) { float v = xs[k][tid]; s = fmaf(v, v, s); }
        xnorm[tid] = -0.72134752044448170f * s;   // -0.5*log2(e)*||x||^2
    }
    __syncthreads();

    float xh[8];
    #pragma unroll
    for (int i = 0; i < 8; ++i) xh[i] = xnorm[ty * 8 + i];

    float racc[8] = {0.f, 0.f, 0.f, 0.f, 0.f, 0.f, 0.f, 0.f};

    for (int t = 0; t < gchunk; t += BN) {
        const int g0 = g0base + t;
        const float* Cs = C + (size_t)g0 * TILE_D;

        __syncthreads();   // previous tile's cs reads complete before overwrite
        #pragma unroll
        for (int p = 0; p < BN; p += 16) {
            int r = p + rbase;
            float4 v;
            v.x = Cs[(size_t)(r + 0) * TILE_D + d];
            v.y = Cs[(size_t)(r + 1) * TILE_D + d];
            v.z = Cs[(size_t)(r + 2) * TILE_D + d];
            v.w = Cs[(size_t)(r + 3) * TILE_D + d];
            *(float4*)&cs[d][r] = v;
        }
        __syncthreads();
        if (tid < BN) {
            float s = 0.f;
            #pragma unroll
            for (int k = 0; k < TILE_D; ++k) { float v = cs[k][tid]; s = fmaf(v, v, s); }
            cnorm[tid] = -0.72134752044448170f * s;
        }
        __syncthreads();

        float acc[8][8] = {};
        #pragma unroll 8
        for (int k = 0; k < TILE_D; ++k) {
            float4 a0 = *(const float4*)&xs[k][ty * 8];
            float4 a1 = *(const float4*)&xs[k][ty * 8 + 4];
            float4 b0 = *(const float4*)&cs[k][tx * 8];
            float4 b1 = *(const float4*)&cs[k][tx * 8 + 4];
            float av[8] = {a0.x, a0.y, a0.z, a0.w, a1.x, a1.y, a1.z, a1.w};
            float bv[8] = {b0.x, b0.y, b0.z, b0.w, b1.x, b1.y, b1.z, b1.w};
            #pragma unroll
            for (int i = 0; i < 8; ++i)
                #pragma unroll
                for (int j = 0; j < 8; ++j)
                    acc[i][j] = fmaf(av[i], bv[j], acc[i][j]);
        }

        float ch[8], wv[8];
        #pragma unroll
        for (int j = 0; j < 8; ++j) {
            ch[j] = cnorm[tx * 8 + j];
            wv[j] = W[g0 + tx * 8 + j];
        }
        #pragma unroll
        for (int i = 0; i < 8; ++i) {
            #pragma unroll
            for (int j = 0; j < 8; ++j) {
                // exp2(log2e*dot - 0.5*log2e*(xn+cn)) = exp(-dist/2)
                float e = fmaf(acc[i][j], 1.4426950408889634f, xh[i] + ch[j]);
                racc[i] = fmaf(exp2f(e), wv[j], racc[i]);
            }
        }
    }

    // ---- reduce partial row sums across tx, then one atomic per row ----
    #pragma unroll
    for (int i = 0; i < 8; ++i) red[ty * 8 + i][tx] = racc[i];
    __syncthreads();
    if (tid < BM) {
        float s = 0.f;
        #pragma unroll
        for (int t = 0; t < 16; ++t) s += red[tid][t];
        atomicAdd(&out[bm0 + tid], s);
    }
}

extern "C" void kernel_launch(void* const* d_in, const int* in_sizes, int n_in,
                              void* d_out, int out_size, void* d_ws, size_t ws_size,
                              hipStream_t stream) {
    const float* X = (const float*)d_in[0];   // [B, 64]
    const float* C = (const float*)d_in[1];   // [G, 64]
    const float* W = (const float*)d_in[2];   // [G]
    float* out = (float*)d_out;               // [B]

    const int B = in_sizes[0] / TILE_D;
    const int G = in_sizes[2];

    hipMemsetAsync(out, 0, (size_t)out_size * sizeof(float), stream);
    dim3 grid(B / BM, GSPLIT);
    gauss_rbf_kernel<<<grid, 256, 0, stream>>>(X, C, W, out, B, G);
}

// Round 2
// 85.092 us; speedup vs baseline: 2.7342x; 2.7342x over previous
//
#include <hip/hip_runtime.h>

// out[b] = sum_g exp(-(||x_b||^2+||c_g||^2-2 x_b.c_g)/2) * w[g]
// B=16384, G=8192, D=64 fp32. v2: split-bf16 3-pass MFMA (hi*hi+hi*lo+lo*hi),
// norms exact fp32 folded into exponent: out = 2^xn_b * sum 2^(L2E*dot+cn_g)*w_g.
// C pre-converted once into d_ws as bf16 hi/lo in MFMA-fragment order ->
// main-loop staging is linear global_load_lds(16B), conflict-free LDS.
// 128x128 tile, 4 waves of 64x64 (2x2 mfma_32x32x16_bf16 tiles), GSPLIT=4.

typedef __attribute__((ext_vector_type(8))) short short8v;
typedef __attribute__((ext_vector_type(16))) float f32x16;
typedef unsigned short u16;
typedef unsigned int u32;

#define L2E   1.4426950408889634f
#define NHL2E 0.72134752044448170f   // L2E/2

__device__ __forceinline__ u16 f2bf(float x){
  u32 u = __float_as_uint(x);
  return (u16)((u + 0x7FFFu + ((u >> 16) & 1u)) >> 16);   // RNE
}
__device__ __forceinline__ float bf2f(u16 h){ return __uint_as_float(((u32)h) << 16); }

__device__ __forceinline__ void gl_lds16(const void* g, void* l){
  __builtin_amdgcn_global_load_lds((const __attribute__((address_space(1))) u32*)g,
                                   (__attribute__((address_space(3))) u32*)l, 16, 0, 0);
}

#define MFMA(a,b,c) __builtin_amdgcn_mfma_f32_32x32x16_bf16(a,b,c,0,0,0)

// ---- one-time: C [G][64] fp32 -> hi/lo bf16 in fragment order + cn[g] ----
// frag unit (cg=g/32, f=k/16, lane): col=cg*32+(l&31), k=f*16+(l>>5)*8+e
__global__ __launch_bounds__(256)
void convert_C(const float* __restrict__ C, u16* __restrict__ Chi,
               u16* __restrict__ Clo, float* __restrict__ cn, int G){
  int g = blockIdx.x*256 + threadIdx.x;
  if (g >= G) return;
  const float* row = C + (size_t)g*64;
  int cg = g >> 5, cl = g & 31;
  float norm = 0.f;
  #pragma unroll
  for (int f=0; f<4; f++){
    #pragma unroll
    for (int h=0; h<2; h++){
      float4 v0 = *(const float4*)(row + f*16 + h*8);
      float4 v1 = *(const float4*)(row + f*16 + h*8 + 4);
      float xv[8] = {v0.x,v0.y,v0.z,v0.w,v1.x,v1.y,v1.z,v1.w};
      u16 hb[8], lb[8];
      #pragma unroll
      for (int e=0;e<8;e++){
        float x = xv[e];
        norm = fmaf(x,x,norm);
        u16 hh = f2bf(x); hb[e]=hh;
        lb[e] = f2bf(x - bf2f(hh));
      }
      size_t u = ((size_t)(cg*4+f)*64 + (size_t)h*32 + cl)*8;
      *(short8v*)(Chi + u) = *(short8v*)hb;
      *(short8v*)(Clo + u) = *(short8v*)lb;
    }
  }
  cn[g] = -NHL2E * norm;
}

__global__ __launch_bounds__(256, 2)
void rbf_mfma(const float* __restrict__ X, const u16* __restrict__ Chi,
              const u16* __restrict__ Clo, const float* __restrict__ cn,
              const float* __restrict__ W, float* __restrict__ out,
              int gchunk){
  __shared__ short8v AhiV[1024], AloV[1024], BhiV[1024], BloV[1024]; // 16KB each
  __shared__ float xnl[128];

  const int tid = threadIdx.x;
  const int l = tid & 63;
  const int w = tid >> 6;
  const int wm = w >> 1, wn = w & 1;   // wave tile: rows wm*64, cols wn*64
  const int bm0 = blockIdx.x * 128;
  const int g0 = blockIdx.y * gchunk;

  // ---- stage A once: convert X rows to hi/lo bf16 fragments in LDS ----
  {
    const int row = w*32 + (l & 31);
    const int h = l >> 5;
    const float* xr = X + (size_t)(bm0 + row)*64;
    #pragma unroll
    for (int f=0; f<4; f++){
      float4 v0 = *(const float4*)(xr + f*16 + h*8);
      float4 v1 = *(const float4*)(xr + f*16 + h*8 + 4);
      float xv[8] = {v0.x,v0.y,v0.z,v0.w,v1.x,v1.y,v1.z,v1.w};
      u16 hb[8], lb[8];
      #pragma unroll
      for (int e=0;e<8;e++){
        u16 hh = f2bf(xv[e]); hb[e]=hh;
        lb[e] = f2bf(xv[e] - bf2f(hh));
      }
      AhiV[(w*4+f)*64 + l] = *(short8v*)hb;
      AloV[(w*4+f)*64 + l] = *(short8v*)lb;
    }
  }
  if (tid < 128){
    const float* xr = X + (size_t)(bm0 + tid)*64;
    float s = 0.f;
    #pragma unroll
    for (int q=0;q<16;q++){
      float4 v = *(const float4*)(xr + q*4);
      s = fmaf(v.x,v.x,s); s = fmaf(v.y,v.y,s);
      s = fmaf(v.z,v.z,s); s = fmaf(v.w,v.w,s);
    }
    xnl[tid] = -NHL2E * s;
  }
  __syncthreads();

  float racc0[16], racc1[16];
  #pragma unroll
  for (int r=0;r<16;r++){ racc0[r]=0.f; racc1[r]=0.f; }

  const int ntiles = gchunk >> 7;
  for (int ct=0; ct<ntiles; ct++){
    // ---- stage B tile (128 cols): linear copy, already fragment-ordered ----
    const u16* sH = Chi + (size_t)(g0 + ct*128)*64;
    const u16* sL = Clo + (size_t)(g0 + ct*128)*64;
    char* dH = (char*)BhiV + w*1024;   // wave-uniform LDS base
    char* dL = (char*)BloV + w*1024;
    #pragma unroll
    for (int i=0;i<4;i++){
      gl_lds16(sH + (size_t)(i*256 + tid)*8, dH + i*4096);
      gl_lds16(sL + (size_t)(i*256 + tid)*8, dL + i*4096);
    }
    asm volatile("s_waitcnt vmcnt(0)" ::: "memory");
    __syncthreads();

    // ---- K-loop: 4 k-steps x 12 MFMA (3 passes x 2x2 tiles) ----
    f32x16 a00={},a01={},a10={},a11={};
    #pragma unroll
    for (int f=0; f<4; f++){
      short8v ah0 = AhiV[((wm*2+0)*4+f)*64 + l];
      short8v ah1 = AhiV[((wm*2+1)*4+f)*64 + l];
      short8v al0 = AloV[((wm*2+0)*4+f)*64 + l];
      short8v al1 = AloV[((wm*2+1)*4+f)*64 + l];
      short8v bh0 = BhiV[((wn*2+0)*4+f)*64 + l];
      short8v bh1 = BhiV[((wn*2+1)*4+f)*64 + l];
      short8v bl0 = BloV[((wn*2+0)*4+f)*64 + l];
      short8v bl1 = BloV[((wn*2+1)*4+f)*64 + l];
      a00 = MFMA(ah0,bh0,a00); a00 = MFMA(ah0,bl0,a00); a00 = MFMA(al0,bh0,a00);
      a01 = MFMA(ah0,bh1,a01); a01 = MFMA(ah0,bl1,a01); a01 = MFMA(al0,bh1,a01);
      a10 = MFMA(ah1,bh0,a10); a10 = MFMA(ah1,bl0,a10); a10 = MFMA(al1,bh0,a10);
      a11 = MFMA(ah1,bh1,a11); a11 = MFMA(ah1,bl1,a11); a11 = MFMA(al1,bh1,a11);
    }

    // ---- epilogue: racc[row] += 2^(L2E*dot + cn_g) * w_g  (col-partial) ----
    const int gc = g0 + ct*128 + wn*64 + (l & 31);
    const float cn0 = cn[gc], cn1 = cn[gc+32];
    const float w0 = W[gc],  w1 = W[gc+32];
    #pragma unroll
    for (int r=0;r<16;r++){
      racc0[r] = fmaf(exp2f(fmaf(a00[r], L2E, cn0)), w0, racc0[r]);
      racc0[r] = fmaf(exp2f(fmaf(a01[r], L2E, cn1)), w1, racc0[r]);
      racc1[r] = fmaf(exp2f(fmaf(a10[r], L2E, cn0)), w0, racc1[r]);
      racc1[r] = fmaf(exp2f(fmaf(a11[r], L2E, cn1)), w1, racc1[r]);
    }
    if (ct+1 < ntiles) __syncthreads();  // guard B overwrite
  }

  // ---- reduce over cols (32-lane halves), fold 2^xn, one atomic per row ----
  #pragma unroll
  for (int tm=0; tm<2; tm++){
    #pragma unroll
    for (int r=0;r<16;r++){
      float v = tm ? racc1[r] : racc0[r];
      v += __shfl_xor(v, 1);
      v += __shfl_xor(v, 2);
      v += __shfl_xor(v, 4);
      v += __shfl_xor(v, 8);
      v += __shfl_xor(v, 16);
      if ((l & 31) == 0){
        int lrow = wm*64 + tm*32 + (r&3) + 8*(r>>2) + 4*(l>>5);
        atomicAdd(&out[bm0 + lrow], v * exp2f(xnl[lrow]));
      }
    }
  }
}

extern "C" void kernel_launch(void* const* d_in, const int* in_sizes, int n_in,
                              void* d_out, int out_size, void* d_ws, size_t ws_size,
                              hipStream_t stream) {
  const float* X = (const float*)d_in[0];   // [B,64]
  const float* C = (const float*)d_in[1];   // [G,64]
  const float* W = (const float*)d_in[2];   // [G]
  float* out = (float*)d_out;               // [B]
  const int B = in_sizes[0] / 64;
  const int G = in_sizes[2];

  u16* Chi = (u16*)d_ws;                    // 1 MB
  u16* Clo = Chi + (size_t)G*64;            // 1 MB
  float* cnw = (float*)(Clo + (size_t)G*64);// 32 KB  (total ~2.06 MB of ws)

  hipMemsetAsync(out, 0, (size_t)B*sizeof(float), stream);
  convert_C<<<G/256, 256, 0, stream>>>(C, Chi, Clo, cnw, G);
  const int gchunk = G/4;
  dim3 grid(B/128, 4);
  rbf_mfma<<<grid, 256, 0, stream>>>(X, Chi, Clo, cnw, W, out, gchunk);
}

// Round 3
// 76.940 us; speedup vs baseline: 3.0239x; 1.1060x over previous
//
#include <hip/hip_runtime.h>

// out[b] = sum_g exp(-(||x_b||^2+||c_g||^2-2 x_b.c_g)/2) * w[g]
// B=16384, G=8192, D=64 fp32.
// v3: split-bf16 3-pass MFMA (hi*hi+hi*lo+lo*hi). A (X) held in registers per
// wave; B (C) double-buffered in LDS with counted s_waitcnt vmcnt(4) + raw
// s_barrier (T3/T4 2-phase, never drain the prefetch). 128-row blocks x 64-col
// tiles, GSPLIT=16 -> 2048 blocks, ~37KB LDS, 3 blocks/CU for cross-wave
// MFMA/VALU overlap. cn/W pre-paired in LDS; exp2 via raw v_exp_f32.

typedef __attribute__((ext_vector_type(8))) short short8v;
typedef __attribute__((ext_vector_type(16))) float f32x16;
typedef unsigned short u16;
typedef unsigned int u32;

#define L2E   1.4426950408889634f
#define NHL2E 0.72134752044448170f   // log2(e)/2
#define GSPLIT 16

__device__ __forceinline__ u16 f2bf(float x){
  u32 u = __float_as_uint(x);
  return (u16)((u + 0x7FFFu + ((u >> 16) & 1u)) >> 16);   // RNE
}
__device__ __forceinline__ float bf2f(u16 h){ return __uint_as_float(((u32)h) << 16); }

__device__ __forceinline__ void gl_lds16(const void* g, void* l){
  __builtin_amdgcn_global_load_lds((const __attribute__((address_space(1))) u32*)g,
                                   (__attribute__((address_space(3))) u32*)l, 16, 0, 0);
}

#define MFMA(a,b,c) __builtin_amdgcn_mfma_f32_32x32x16_bf16(a,b,c,0,0,0)

// ---- one-time: C [G][64] fp32 -> hi/lo bf16 in fragment order + (cn,w) pairs ----
// frag unit (cg=g/32, f=k/16): lane part (h=l>>5, cl=l&31): col=cg*32+cl, k=f*16+h*8+e
__global__ __launch_bounds__(256)
void convert_C(const float* __restrict__ C, const float* __restrict__ W,
               u16* __restrict__ Chi, u16* __restrict__ Clo,
               float2* __restrict__ cw, int G){
  int g = blockIdx.x*256 + threadIdx.x;
  if (g >= G) return;
  const float* row = C + (size_t)g*64;
  int cg = g >> 5, cl = g & 31;
  float norm = 0.f;
  #pragma unroll
  for (int f=0; f<4; f++){
    #pragma unroll
    for (int h=0; h<2; h++){
      float4 v0 = *(const float4*)(row + f*16 + h*8);
      float4 v1 = *(const float4*)(row + f*16 + h*8 + 4);
      float xv[8] = {v0.x,v0.y,v0.z,v0.w,v1.x,v1.y,v1.z,v1.w};
      u16 hb[8], lb[8];
      #pragma unroll
      for (int e=0;e<8;e++){
        float x = xv[e];
        norm = fmaf(x,x,norm);
        u16 hh = f2bf(x); hb[e]=hh;
        lb[e] = f2bf(x - bf2f(hh));
      }
      size_t u = ((size_t)(cg*4+f)*64 + (size_t)h*32 + cl)*8;
      *(short8v*)(Chi + u) = *(short8v*)hb;
      *(short8v*)(Clo + u) = *(short8v*)lb;
    }
  }
  cw[g] = make_float2(-NHL2E * norm, W[g]);
}

__global__ __launch_bounds__(256, 3)
void rbf_mfma(const float* __restrict__ X, const u16* __restrict__ Chi,
              const u16* __restrict__ Clo, const float2* __restrict__ cw,
              float* __restrict__ out, int gchunk){
  __shared__ short8v Bsh[2][2][512];   // [dbuf][hi/lo][frag-unit], 32 KB
  __shared__ float2 cwsh[512];         // (cn, w) for this block's g-chunk, 4 KB
  __shared__ float xnl[128];

  const int tid = threadIdx.x;
  const int l = tid & 63;
  const int w = tid >> 6;
  const int h = l >> 5;
  const int bm0 = blockIdx.x * 128;
  const int g0 = blockIdx.y * gchunk;
  const int nt = gchunk >> 6;          // 64-col tiles

  // ---- A fragments (32 rows per wave) into registers, hi/lo split ----
  short8v ah[4], al[4];
  {
    const int row = w*32 + (l & 31);
    const float* xr = X + (size_t)(bm0 + row)*64;
    #pragma unroll
    for (int f=0; f<4; f++){
      float4 v0 = *(const float4*)(xr + f*16 + h*8);
      float4 v1 = *(const float4*)(xr + f*16 + h*8 + 4);
      float xv[8] = {v0.x,v0.y,v0.z,v0.w,v1.x,v1.y,v1.z,v1.w};
      u16 hb[8], lb[8];
      #pragma unroll
      for (int e=0;e<8;e++){
        u16 hh = f2bf(xv[e]); hb[e]=hh;
        lb[e] = f2bf(xv[e] - bf2f(hh));
      }
      ah[f] = *(short8v*)hb;
      al[f] = *(short8v*)lb;
    }
  }
  if (tid < 128){
    const float* xr = X + (size_t)(bm0 + tid)*64;
    float s = 0.f;
    #pragma unroll
    for (int q=0;q<16;q++){
      float4 v = *(const float4*)(xr + q*4);
      s = fmaf(v.x,v.x,s); s = fmaf(v.y,v.y,s);
      s = fmaf(v.z,v.z,s); s = fmaf(v.w,v.w,s);
    }
    xnl[tid] = -NHL2E * s;
  }
  __syncthreads();   // xnl visible; full drain OK here (prefetch not yet issued)

  // ---- prologue staging: cw pairs (1 round) + tile 0 (4 rounds) ----
  gl_lds16((const char*)(cw + g0) + (size_t)tid*16, (char*)cwsh + w*1024);
  {
    const u16* sH = Chi + (size_t)g0*64;
    const u16* sL = Clo + (size_t)g0*64;
    char* dH = (char*)&Bsh[0][0][0] + w*1024;
    char* dL = (char*)&Bsh[0][1][0] + w*1024;
    gl_lds16(sH + (size_t)tid*8,       dH);
    gl_lds16(sH + (size_t)(256+tid)*8, dH + 4096);
    gl_lds16(sL + (size_t)tid*8,       dL);
    gl_lds16(sL + (size_t)(256+tid)*8, dL + 4096);
  }

  float racc[16];
  #pragma unroll
  for (int r=0;r<16;r++) racc[r] = 0.f;

  int cur = 0;
  for (int ct=0; ct<nt; ct++){
    // ---- issue next tile's stage BEFORE waiting on current (T14/T3) ----
    if (ct+1 < nt){
      const u16* sH = Chi + (size_t)(g0 + (ct+1)*64)*64;
      const u16* sL = Clo + (size_t)(g0 + (ct+1)*64)*64;
      char* dH = (char*)&Bsh[cur^1][0][0] + w*1024;
      char* dL = (char*)&Bsh[cur^1][1][0] + w*1024;
      gl_lds16(sH + (size_t)tid*8,       dH);
      gl_lds16(sH + (size_t)(256+tid)*8, dH + 4096);
      gl_lds16(sL + (size_t)tid*8,       dL);
      gl_lds16(sL + (size_t)(256+tid)*8, dL + 4096);
      asm volatile("s_waitcnt vmcnt(4)" ::: "memory");   // cur's 4 loads done
    } else {
      asm volatile("s_waitcnt vmcnt(0)" ::: "memory");
    }
    __builtin_amdgcn_s_barrier();
    __builtin_amdgcn_sched_barrier(0);

    // ---- 24 MFMA: 2 col-tiles x 3 passes x 4 k-steps ----
    f32x16 a0 = {}, a1 = {};
    __builtin_amdgcn_s_setprio(1);
    #pragma unroll
    for (int f=0; f<4; f++){
      short8v bh0 = Bsh[cur][0][(0*4+f)*64 + l];
      short8v bh1 = Bsh[cur][0][(1*4+f)*64 + l];
      short8v bl0 = Bsh[cur][1][(0*4+f)*64 + l];
      short8v bl1 = Bsh[cur][1][(1*4+f)*64 + l];
      a0 = MFMA(ah[f],bh0,a0); a0 = MFMA(ah[f],bl0,a0); a0 = MFMA(al[f],bh0,a0);
      a1 = MFMA(ah[f],bh1,a1); a1 = MFMA(ah[f],bl1,a1); a1 = MFMA(al[f],bh1,a1);
    }
    __builtin_amdgcn_s_setprio(0);

    // ---- epilogue: racc += 2^(L2E*dot + cn)*w for both col halves ----
    float2 c0 = cwsh[ct*64 + (l & 31)];
    float2 c1 = cwsh[ct*64 + 32 + (l & 31)];
    #pragma unroll
    for (int r=0;r<16;r++){
      racc[r] = fmaf(__builtin_amdgcn_exp2f(fmaf(a0[r], L2E, c0.x)), c0.y, racc[r]);
      racc[r] = fmaf(__builtin_amdgcn_exp2f(fmaf(a1[r], L2E, c1.x)), c1.y, racc[r]);
    }

    asm volatile("s_waitcnt lgkmcnt(0)" ::: "memory");   // my reads of cur retired
    __builtin_amdgcn_sched_barrier(0);
    __builtin_amdgcn_s_barrier();                        // cur safe to overwrite
    cur ^= 1;
  }

  // ---- reduce over 32 col-lanes, fold 2^xn, one atomic per row ----
  #pragma unroll
  for (int r=0;r<16;r++){
    float v = racc[r];
    v += __shfl_xor(v, 1);
    v += __shfl_xor(v, 2);
    v += __shfl_xor(v, 4);
    v += __shfl_xor(v, 8);
    v += __shfl_xor(v, 16);
    if ((l & 31) == 0){
      int rl = w*32 + (r&3) + 8*(r>>2) + 4*h;
      atomicAdd(&out[bm0 + rl], v * __builtin_amdgcn_exp2f(xnl[rl]));
    }
  }
}

extern "C" void kernel_launch(void* const* d_in, const int* in_sizes, int n_in,
                              void* d_out, int out_size, void* d_ws, size_t ws_size,
                              hipStream_t stream) {
  const float* X = (const float*)d_in[0];   // [B,64]
  const float* C = (const float*)d_in[1];   // [G,64]
  const float* W = (const float*)d_in[2];   // [G]
  float* out = (float*)d_out;               // [B]
  const int B = in_sizes[0] / 64;
  const int G = in_sizes[2];

  u16* Chi = (u16*)d_ws;                         // 1 MB
  u16* Clo = Chi + (size_t)G*64;                 // 1 MB
  float2* cw = (float2*)(Clo + (size_t)G*64);    // 64 KB

  hipMemsetAsync(out, 0, (size_t)B*sizeof(float), stream);
  convert_C<<<G/256, 256, 0, stream>>>(C, W, Chi, Clo, cw, G);
  const int gchunk = G / GSPLIT;
  dim3 grid(B/128, GSPLIT);
  rbf_mfma<<<grid, 256, 0, stream>>>(X, Chi, Clo, cw, out, gchunk);
}

// Round 4
// 68.981 us; speedup vs baseline: 3.3729x; 1.1154x over previous
//
#include <hip/hip_runtime.h>

// out[b] = sum_g exp(-(||x_b||^2+||c_g||^2-2 x_b.c_g)/2) * w[g]
// B=16384, G=8192, D=64 fp32.
// v4: split-bf16 3-pass MFMA, ZERO LDS / ZERO barriers. R3 post-mortem showed
// LDS BW capped MfmaUtil at 37.5% (4 waves re-reading identical B frags).
// Now: A (64 rows/wave) in registers; B fragments streamed global->reg
// (Chi/Clo pre-laid in MFMA fragment order), ping-pong prefetch 1 f-step
// ahead. All 4 waves of a block read IDENTICAL B addresses -> L1 hits.
// Each wave: 64 rows x 1024-col sweep (16 tiles of 64 cols). 512 blocks,
// 2/CU, exactly one dispatch round.

typedef __attribute__((ext_vector_type(8))) short short8v;
typedef __attribute__((ext_vector_type(16))) float f32x16;
typedef unsigned short u16;
typedef unsigned int u32;

#define L2E   1.4426950408889634f
#define NHL2E 0.72134752044448170f   // log2(e)/2
#define GSPLIT 8                     // gchunk = 1024 cols per wave

__device__ __forceinline__ u16 f2bf(float x){
  u32 u = __float_as_uint(x);
  return (u16)((u + 0x7FFFu + ((u >> 16) & 1u)) >> 16);   // RNE
}
__device__ __forceinline__ float bf2f(u16 h){ return __uint_as_float(((u32)h) << 16); }

#define MFMA(a,b,c) __builtin_amdgcn_mfma_f32_32x32x16_bf16(a,b,c,0,0,0)

// ---- one-time: C [G][64] fp32 -> hi/lo bf16 in fragment order + (cn,w) ----
// layout (cg=g/32, f=k/16, h, cl=g&31): u16 index ((cg*4+f)*64 + h*32 + cl)*8 + e
// one thread per (g, f): 4x parallel vs R3's per-g.
__global__ __launch_bounds__(256)
void convert_C(const float* __restrict__ C, const float* __restrict__ W,
               u16* __restrict__ Chi, u16* __restrict__ Clo,
               float2* __restrict__ cw, int G){
  int idx = blockIdx.x*256 + threadIdx.x;
  int g = idx >> 2, f = idx & 3;
  if (g >= G) return;
  const float* row = C + (size_t)g*64 + f*16;
  int cg = g >> 5, cl = g & 31;
  float norm = 0.f;
  u16 hb[16], lb[16];
  #pragma unroll
  for (int q=0; q<4; q++){
    float4 v = *(const float4*)(row + q*4);
    float xv[4] = {v.x, v.y, v.z, v.w};
    #pragma unroll
    for (int e=0; e<4; e++){
      float x = xv[e];
      norm = fmaf(x, x, norm);
      u16 hh = f2bf(x); hb[q*4+e] = hh;
      lb[q*4+e] = f2bf(x - bf2f(hh));
    }
  }
  norm += __shfl_xor(norm, 1);   // reduce over the 4 f-lanes of this g
  norm += __shfl_xor(norm, 2);
  size_t u = ((size_t)(cg*4 + f)*64 + cl)*8;
  *(short8v*)(Chi + u)        = *(short8v*)hb;        // h=0 (k offsets 0..7)
  *(short8v*)(Chi + u + 256)  = *(short8v*)(hb + 8);  // h=1 (k offsets 8..15)
  *(short8v*)(Clo + u)        = *(short8v*)lb;
  *(short8v*)(Clo + u + 256)  = *(short8v*)(lb + 8);
  if (f == 0) cw[g] = make_float2(-NHL2E*norm, W[g]);
}

__global__ __launch_bounds__(256, 2)
void rbf_mfma(const float* __restrict__ X, const u16* __restrict__ Chi,
              const u16* __restrict__ Clo, const float2* __restrict__ cw,
              float* __restrict__ out){
  const int tid = threadIdx.x;
  const int l  = tid & 63;
  const int cl = l & 31;
  const int h  = l >> 5;
  const int w  = tid >> 6;
  const int b  = blockIdx.x;
  const int gp = b & 7;                  // all 4 waves share gp -> L1 B-sharing
  const int rowgroup = (b >> 3)*4 + w;
  const int rows0 = rowgroup * 64;
  const int g0 = gp * 1024;

  // ---- A: 2 row-frags (64 rows) converted to hi/lo bf16 in registers ----
  short8v ah[2][4], al[2][4];
  float xn[2];
  #pragma unroll
  for (int rf=0; rf<2; rf++){
    const float* xr = X + (size_t)(rows0 + rf*32 + cl)*64;
    float s = 0.f;
    #pragma unroll
    for (int f=0; f<4; f++){
      float4 v0 = *(const float4*)(xr + f*16 + h*8);
      float4 v1 = *(const float4*)(xr + f*16 + h*8 + 4);
      float xv[8] = {v0.x,v0.y,v0.z,v0.w,v1.x,v1.y,v1.z,v1.w};
      u16 hb[8], lb[8];
      #pragma unroll
      for (int e=0;e<8;e++){
        float x = xv[e];
        s = fmaf(x, x, s);
        u16 hh = f2bf(x); hb[e]=hh;
        lb[e] = f2bf(x - bf2f(hh));
      }
      ah[rf][f] = *(short8v*)hb;
      al[rf][f] = *(short8v*)lb;
    }
    s += __shfl_xor(s, 32);              // other half of the row's norm
    xn[rf] = -NHL2E * s;
  }

  // ---- B fragment stream bases: byte addr = base + t*8192 + cf*4096 + f*1024 ----
  const char* baseH = (const char*)Chi + (size_t)gp*131072 + (size_t)l*16;
  const char* baseL = (const char*)Clo + (size_t)gp*131072 + (size_t)l*16;

  short8v bh0[2], bh1[2], bl0[2], bl1[2];
  bh0[0] = *(const short8v*)(baseH);
  bh1[0] = *(const short8v*)(baseH + 4096);
  bl0[0] = *(const short8v*)(baseL);
  bl1[0] = *(const short8v*)(baseL + 4096);

  float racc[2][16];
  #pragma unroll
  for (int rf=0; rf<2; rf++)
    #pragma unroll
    for (int r=0;r<16;r++) racc[rf][r] = 0.f;

  for (int t = 0; t < 16; ++t){
    f32x16 a00={}, a01={}, a10={}, a11={};
    #pragma unroll
    for (int f = 0; f < 4; ++f){
      const int p = f & 1, q = p ^ 1;
      // prefetch next f-step (wraps harmlessly to t=0,f=0 at the very end)
      const int nf = (f + 1) & 3;
      const int nt = (f == 3) ? ((t + 1) & 15) : t;
      size_t off = (size_t)nt*8192 + (size_t)nf*1024;
      bh0[q] = *(const short8v*)(baseH + off);
      bh1[q] = *(const short8v*)(baseH + off + 4096);
      bl0[q] = *(const short8v*)(baseL + off);
      bl1[q] = *(const short8v*)(baseL + off + 4096);
      // 12 MFMA: hh, hl, lh passes, round-robin across 4 acc chains
      a00 = MFMA(ah[0][f], bh0[p], a00);
      a01 = MFMA(ah[0][f], bh1[p], a01);
      a10 = MFMA(ah[1][f], bh0[p], a10);
      a11 = MFMA(ah[1][f], bh1[p], a11);
      a00 = MFMA(ah[0][f], bl0[p], a00);
      a01 = MFMA(ah[0][f], bl1[p], a01);
      a10 = MFMA(ah[1][f], bl0[p], a10);
      a11 = MFMA(ah[1][f], bl1[p], a11);
      a00 = MFMA(al[0][f], bh0[p], a00);
      a01 = MFMA(al[0][f], bh1[p], a01);
      a10 = MFMA(al[1][f], bh0[p], a10);
      a11 = MFMA(al[1][f], bh1[p], a11);
    }
    // ---- epilogue: racc += 2^(L2E*dot + cn) * w ----
    float2 c0 = cw[g0 + t*64 + cl];
    float2 c1 = cw[g0 + t*64 + 32 + cl];
    #pragma unroll
    for (int r=0;r<16;r++){
      racc[0][r] = fmaf(__builtin_amdgcn_exp2f(fmaf(a00[r], L2E, c0.x)), c0.y, racc[0][r]);
      racc[0][r] = fmaf(__builtin_amdgcn_exp2f(fmaf(a01[r], L2E, c1.x)), c1.y, racc[0][r]);
      racc[1][r] = fmaf(__builtin_amdgcn_exp2f(fmaf(a10[r], L2E, c0.x)), c0.y, racc[1][r]);
      racc[1][r] = fmaf(__builtin_amdgcn_exp2f(fmaf(a11[r], L2E, c1.x)), c1.y, racc[1][r]);
    }
  }

  // ---- reduce over 32 col-lanes, fold 2^xn, one atomic per row ----
  #pragma unroll
  for (int rf=0; rf<2; rf++){
    #pragma unroll
    for (int r=0;r<16;r++){
      float v = racc[rf][r];
      v += __shfl_xor(v, 1);
      v += __shfl_xor(v, 2);
      v += __shfl_xor(v, 4);
      v += __shfl_xor(v, 8);
      v += __shfl_xor(v, 16);
      const int rit = (r&3) + 8*(r>>2) + 4*h;       // row within 32-row tile
      const float xnv = __shfl(xn[rf], rit);        // norm lives at lane rit
      if (cl == 0)
        atomicAdd(&out[rows0 + rf*32 + rit], v * __builtin_amdgcn_exp2f(xnv));
    }
  }
}

extern "C" void kernel_launch(void* const* d_in, const int* in_sizes, int n_in,
                              void* d_out, int out_size, void* d_ws, size_t ws_size,
                              hipStream_t stream) {
  const float* X = (const float*)d_in[0];   // [B,64]
  const float* C = (const float*)d_in[1];   // [G,64]
  const float* W = (const float*)d_in[2];   // [G]
  float* out = (float*)d_out;               // [B]
  const int B = in_sizes[0] / 64;
  const int G = in_sizes[2];

  u16* Chi = (u16*)d_ws;                         // 1 MB
  u16* Clo = Chi + (size_t)G*64;                 // 1 MB
  float2* cw = (float2*)(Clo + (size_t)G*64);    // 64 KB

  hipMemsetAsync(out, 0, (size_t)B*sizeof(float), stream);
  convert_C<<<(G*4)/256, 256, 0, stream>>>(C, W, Chi, Clo, cw, G);
  rbf_mfma<<<(B/128)*(GSPLIT/2), 256, 0, stream>>>(X, Chi, Clo, cw, out);
}

// Round 5
// 68.244 us; speedup vs baseline: 3.4093x; 1.0108x over previous
//
#include <hip/hip_runtime.h>

// out[b] = sum_g exp(-(||x_b||^2+||c_g||^2-2 x_b.c_g)/2) * w[g]
// B=16384, G=8192, D=64 fp32.
// v5: split-bf16 3-pass MFMA, zero LDS/zero barriers (v4 structure) +
// ACC DOUBLE-BUFFERING (T15): two named acc sets so epilogue(t-1) issues
// while the matrix pipe drains MFMA(t) -> intra-wave MFMA/epilogue overlap.
// R4 post-mortem: matrix pipe is CU-level (8 cyc per 32x32x16); per-wave
// program-order M->E serialization left it idle 2/3 of the time.
// Tile: 64 rows x 32 cols per t (2 rowfrag chains), 32 t-steps of 1024 cols.
// ~205 VGPR -> 2 waves/SIMD; 512 blocks = 2/CU, one dispatch round.

typedef __attribute__((ext_vector_type(8))) short short8v;
typedef __attribute__((ext_vector_type(16))) float f32x16;
typedef unsigned short u16;
typedef unsigned int u32;

#define L2E   1.4426950408889634f
#define NHL2E 0.72134752044448170f   // log2(e)/2
#define GSPLIT 8                     // 1024 cols per wave sweep

__device__ __forceinline__ u16 f2bf(float x){
  u32 u = __float_as_uint(x);
  return (u16)((u + 0x7FFFu + ((u >> 16) & 1u)) >> 16);   // RNE
}
__device__ __forceinline__ float bf2f(u16 h){ return __uint_as_float(((u32)h) << 16); }

#define MFMA(a,b,c) __builtin_amdgcn_mfma_f32_32x32x16_bf16(a,b,c,0,0,0)

// ---- one-time: C [G][64] fp32 -> hi/lo bf16 in fragment order + (cn,w) ----
// layout (cg=g/32, f, h, cl): u16 index ((cg*4+f)*64 + h*32 + cl)*8 + e
__global__ __launch_bounds__(256)
void convert_C(const float* __restrict__ C, const float* __restrict__ W,
               u16* __restrict__ Chi, u16* __restrict__ Clo,
               float2* __restrict__ cw, int G){
  int idx = blockIdx.x*256 + threadIdx.x;
  int g = idx >> 2, f = idx & 3;
  if (g >= G) return;
  const float* row = C + (size_t)g*64 + f*16;
  int cg = g >> 5, cl = g & 31;
  float norm = 0.f;
  u16 hb[16], lb[16];
  #pragma unroll
  for (int q=0; q<4; q++){
    float4 v = *(const float4*)(row + q*4);
    float xv[4] = {v.x, v.y, v.z, v.w};
    #pragma unroll
    for (int e=0; e<4; e++){
      float x = xv[e];
      norm = fmaf(x, x, norm);
      u16 hh = f2bf(x); hb[q*4+e] = hh;
      lb[q*4+e] = f2bf(x - bf2f(hh));
    }
  }
  norm += __shfl_xor(norm, 1);
  norm += __shfl_xor(norm, 2);
  size_t u = ((size_t)(cg*4 + f)*64 + cl)*8;
  *(short8v*)(Chi + u)        = *(short8v*)hb;
  *(short8v*)(Chi + u + 256)  = *(short8v*)(hb + 8);
  *(short8v*)(Clo + u)        = *(short8v*)lb;
  *(short8v*)(Clo + u + 256)  = *(short8v*)(lb + 8);
  if (f == 0) cw[g] = make_float2(-NHL2E*norm, W[g]);
}

__global__ __launch_bounds__(256, 2)
void rbf_mfma(const float* __restrict__ X, const u16* __restrict__ Chi,
              const u16* __restrict__ Clo, const float2* __restrict__ cw,
              float* __restrict__ out){
  const int tid = threadIdx.x;
  const int l  = tid & 63;
  const int cl = l & 31;
  const int h  = l >> 5;
  const int w  = tid >> 6;
  const int b  = blockIdx.x;
  const int gp = b & 7;                  // 4 waves share gp -> L1/L2 B-sharing
  const int rows0 = ((b >> 3)*4 + w) * 64;

  // ---- A: 2 row-frags (64 rows) hi/lo bf16 in registers ----
  short8v ah[2][4], al[2][4];
  float xn[2];
  #pragma unroll
  for (int rf=0; rf<2; rf++){
    const float* xr = X + (size_t)(rows0 + rf*32 + cl)*64;
    float s = 0.f;
    #pragma unroll
    for (int f=0; f<4; f++){
      float4 v0 = *(const float4*)(xr + f*16 + h*8);
      float4 v1 = *(const float4*)(xr + f*16 + h*8 + 4);
      float xv[8] = {v0.x,v0.y,v0.z,v0.w,v1.x,v1.y,v1.z,v1.w};
      u16 hb[8], lb[8];
      #pragma unroll
      for (int e=0;e<8;e++){
        float x = xv[e];
        s = fmaf(x, x, s);
        u16 hh = f2bf(x); hb[e]=hh;
        lb[e] = f2bf(x - bf2f(hh));
      }
      ah[rf][f] = *(short8v*)hb;
      al[rf][f] = *(short8v*)lb;
    }
    s += __shfl_xor(s, 32);
    xn[rf] = -NHL2E * s;
  }

  // B stream: byte addr = base + t*4096 + f*1024 (+l*16), t = col-frag 0..31
  const char* baseH = (const char*)Chi + (size_t)gp*131072 + (size_t)l*16;
  const char* baseL = (const char*)Clo + (size_t)gp*131072 + (size_t)l*16;
  const float2* cwp = cw + gp*1024 + cl;

  short8v bh[2], bl[2];
  bh[0] = *(const short8v*)baseH;        // (t=0, f=0)
  bl[0] = *(const short8v*)baseL;

  float racc0[16], racc1[16];
  #pragma unroll
  for (int r=0;r<16;r++){ racc0[r]=0.f; racc1[r]=0.f; }

  f32x16 aE0, aE1, aO0, aO1;
  float2 cwE, cwO;

  // MFMA block for tile T into acc set (A0,A1); prefetches cw[T] for its EPI
  // and B one f-step ahead (depth-1 ping-pong, parity p=f&1 static).
  #define MSTEP(T, A0, A1, CWR) do {                                        \
    const int t_ = (T);                                                     \
    CWR = cwp[t_*32];                                                       \
    A0 = (f32x16){}; A1 = (f32x16){};                                       \
    __builtin_amdgcn_s_setprio(1);                                          \
    _Pragma("unroll")                                                       \
    for (int f=0; f<4; ++f){                                                \
      const int p = f & 1, q = p ^ 1;                                       \
      const int nf = (f + 1) & 3;                                           \
      const int nt = (f == 3) ? ((t_ + 1) & 31) : t_;                       \
      const size_t off = (size_t)nt*4096 + (size_t)nf*1024;                 \
      bh[q] = *(const short8v*)(baseH + off);                               \
      bl[q] = *(const short8v*)(baseL + off);                               \
      A0 = MFMA(ah[0][f], bh[p], A0);                                       \
      A1 = MFMA(ah[1][f], bh[p], A1);                                       \
      A0 = MFMA(ah[0][f], bl[p], A0);                                       \
      A1 = MFMA(ah[1][f], bl[p], A1);                                       \
      A0 = MFMA(al[0][f], bh[p], A0);                                       \
      A1 = MFMA(al[1][f], bh[p], A1);                                       \
    }                                                                       \
    __builtin_amdgcn_s_setprio(0);                                          \
  } while(0)

  #define EPI(A0, A1, CWR) do {                                             \
    _Pragma("unroll")                                                       \
    for (int r=0;r<16;++r){                                                 \
      racc0[r] = fmaf(__builtin_amdgcn_exp2f(fmaf(A0[r], L2E, CWR.x)),      \
                      CWR.y, racc0[r]);                                     \
      racc1[r] = fmaf(__builtin_amdgcn_exp2f(fmaf(A1[r], L2E, CWR.x)),      \
                      CWR.y, racc1[r]);                                     \
    }                                                                       \
  } while(0)

  MSTEP(0, aE0, aE1, cwE);
  #pragma unroll 1
  for (int tp = 0; tp < 15; ++tp){
    MSTEP(2*tp + 1, aO0, aO1, cwO);   // issue MFMAs(odd t)
    EPI(aE0, aE1, cwE);               // epilogue(even t) overlaps their drain
    MSTEP(2*tp + 2, aE0, aE1, cwE);   // issue MFMAs(even t+2)
    EPI(aO0, aO1, cwO);               // epilogue(odd t) overlaps
  }
  MSTEP(31, aO0, aO1, cwO);
  EPI(aE0, aE1, cwE);                 // t=30
  EPI(aO0, aO1, cwO);                 // t=31

  // ---- reduce over 32 col-lanes, fold 2^xn, one atomic per row ----
  #pragma unroll
  for (int rf=0; rf<2; rf++){
    #pragma unroll
    for (int r=0;r<16;r++){
      float v = rf ? racc1[r] : racc0[r];
      v += __shfl_xor(v, 1);
      v += __shfl_xor(v, 2);
      v += __shfl_xor(v, 4);
      v += __shfl_xor(v, 8);
      v += __shfl_xor(v, 16);
      const int rit = (r&3) + 8*(r>>2) + 4*h;
      const float xnv = __shfl(xn[rf], rit);
      if (cl == 0)
        atomicAdd(&out[rows0 + rf*32 + rit], v * __builtin_amdgcn_exp2f(xnv));
    }
  }
}

extern "C" void kernel_launch(void* const* d_in, const int* in_sizes, int n_in,
                              void* d_out, int out_size, void* d_ws, size_t ws_size,
                              hipStream_t stream) {
  const float* X = (const float*)d_in[0];   // [B,64]
  const float* C = (const float*)d_in[1];   // [G,64]
  const float* W = (const float*)d_in[2];   // [G]
  float* out = (float*)d_out;               // [B]
  const int B = in_sizes[0] / 64;
  const int G = in_sizes[2];

  u16* Chi = (u16*)d_ws;                         // 1 MB
  u16* Clo = Chi + (size_t)G*64;                 // 1 MB
  float2* cw = (float2*)(Clo + (size_t)G*64);    // 64 KB

  hipMemsetAsync(out, 0, (size_t)B*sizeof(float), stream);
  convert_C<<<(G*4)/256, 256, 0, stream>>>(C, W, Chi, Clo, cw, G);
  rbf_mfma<<<(B/128)*(GSPLIT/2), 256, 0, stream>>>(X, Chi, Clo, cw, out);
}